// Round 9
// baseline (24.894 us; speedup 1.0000x reference)
//
#include <hip/hip_runtime.h>

// RuleNet: out[b] = 5 + sum_c rw[c] * min_j( mu[c,j]*x[b,j] + (1-mu[c,j]) )
// with x = [x0, 1-x0], mu = sigmoid(conjunctions).
// Rewrite: fit(b,c) = 1 - max_v max( mu1[c,v]*(1-x0[b,v]), mu2[c,v]*x0[b,v] )
//          mu1*(1-x) = fma(-mu1, x, mu1).
//
// R9: test the mu-stream-bound hypothesis. BPB 8->16 halves total mu VMEM
// traffic (128MB -> 64MB); VALU work conserved. Everything else as R8:
// pinned-VGPR mu (anti-sink asm), LDS x broadcast, fused atomic epilogue.

#define B_    1024
#define C_    512
#define V_    256
#define TWOV  512

#define CPW    64              // conjunctions per wave (one per lane)
#define NCHUNK (C_ / CPW)      // 8 c-chunks
#define BPB    16              // batches per block  <-- doubled (mu reuse 2x)
#define NBG    (B_ / BPB)      // 64 b-groups
#define WAVES  8               // waves per block, v-range split 8 x 32
#define VPW    32              // v per wave
#define HVP    8               // float4 (v-pairs) per half: 16 v per half

// ---------- kernel 1: sigmoid + transpose, plus out[b]=5.0 init ----------
// float2 element (v>>1)*1024 + c*2 + (v&1) = (mu1[v], mu2[v])
//  => float4 muT4[vp][c] = (mu1[2vp], mu2[2vp], mu1[2vp+1], mu2[2vp+1])
__global__ __launch_bounds__(256) void k_prep(const float* __restrict__ conj,
                                              float2* __restrict__ muT2,
                                              float* __restrict__ out) {
    const int c = blockIdx.x;        // 512 blocks
    const int v = threadIdx.x;       // 256 threads, coalesced loads
    if (c < 4) out[c * 256 + v] = 5.0f;   // init accumulator target
    float z1 = conj[(size_t)c * TWOV + v];
    float z2 = conj[(size_t)c * TWOV + V_ + v];
    float m1 = 1.0f / (1.0f + __expf(-z1));
    float m2 = 1.0f / (1.0f + __expf(-z2));
    muT2[(size_t)(v >> 1) * (2 * C_) + c * 2 + (v & 1)] = make_float2(m1, m2);
}

// ---------- kernel 2: main fuzzy-AND + fused weighted-sum epilogue ----------
__global__ __launch_bounds__(512, 4) void k_main(const float* __restrict__ x0,
                                                 const float4* __restrict__ muT4,
                                                 const float* __restrict__ rw,
                                                 float* __restrict__ out) {
    const int tid   = threadIdx.x;
    const int lane  = tid & 63;
    const int wave  = tid >> 6;
    const int chunk = blockIdx.y;                // 8 chunks of 64 c
    const int c     = chunk * CPW + lane;        // this lane's conjunction
    const int bg    = blockIdx.x;                // 64 groups of 16 batches
    const int v0    = wave * VPW;                // this wave's v-range

    __shared__ float4 xs[BPB * V_ / 4];          // 16 KB: x rows of this b-group
    __shared__ float  red[BPB * WAVES * 64];     // 32 KB: cross-wave max combine

    // stage x: 512 threads, two coalesced float4 each (16 rows x 1KB)
    {
        const float4* xg = reinterpret_cast<const float4*>(x0 + (size_t)bg * BPB * V_);
        xs[tid]       = xg[tid];
        xs[tid + 512] = xg[tid + 512];
    }

    const float4* mup = muT4 + (size_t)(v0 >> 1) * C_ + c;

    float m[BPB];
#pragma unroll
    for (int i = 0; i < BPB; ++i) m[i] = 0.0f;

    __syncthreads();

#pragma unroll
    for (int h = 0; h < 2; ++h) {
        // this half's mu slice (16 v): loaded once, PINNED in VGPRs (anti-sink)
        float4 mr[HVP];
#pragma unroll
        for (int p = 0; p < HVP; ++p)
            mr[p] = mup[(size_t)(h * HVP + p) * C_];
#pragma unroll
        for (int p = 0; p < HVP; ++p)
            asm volatile("" : "+v"(mr[p].x), "+v"(mr[p].y), "+v"(mr[p].z), "+v"(mr[p].w));

#pragma unroll
        for (int bi = 0; bi < BPB; ++bi) {
            // wave-uniform LDS reads: same addr across lanes = free broadcast
            const int xb = bi * (V_ / 4) + (v0 >> 2) + h * 4;
            float4 xa = xs[xb + 0];
            float4 xc = xs[xb + 1];
            float4 xd = xs[xb + 2];
            float4 xe = xs[xb + 3];
            float mm = m[bi];
#define STEP(P, XA, XB) \
            mm = fmaxf(mm, fmaxf(__builtin_fmaf(-mr[P].x, (XA), mr[P].x), mr[P].y * (XA))); \
            mm = fmaxf(mm, fmaxf(__builtin_fmaf(-mr[P].z, (XB), mr[P].z), mr[P].w * (XB)));
            STEP(0, xa.x, xa.y)  STEP(1, xa.z, xa.w)
            STEP(2, xc.x, xc.y)  STEP(3, xc.z, xc.w)
            STEP(4, xd.x, xd.y)  STEP(5, xd.z, xd.w)
            STEP(6, xe.x, xe.y)  STEP(7, xe.z, xe.w)
#undef STEP
            m[bi] = mm;
        }
    }

    // cross-wave max combine: red[bi][wave][lane] (tid-consecutive writes)
#pragma unroll
    for (int bi = 0; bi < BPB; ++bi)
        red[bi * (WAVES * 64) + tid] = m[bi];
    __syncthreads();

    // wave w finishes batches bi = w and bi = w + 8 (all 8 waves in parallel)
    const float rwc = rw[c];
    float m0 = red[wave * (WAVES * 64) + lane];
    float m1 = red[(wave + 8) * (WAVES * 64) + lane];
#pragma unroll
    for (int k = 1; k < WAVES; ++k) {
        m0 = fmaxf(m0, red[wave * (WAVES * 64) + k * 64 + lane]);
        m1 = fmaxf(m1, red[(wave + 8) * (WAVES * 64) + k * 64 + lane]);
    }
    float s0 = rwc * (1.0f - m0);
    float s1 = rwc * (1.0f - m1);
    // butterfly sums across 64 lanes = sum over this chunk's 64 conjunctions
#pragma unroll
    for (int d = 1; d < 64; d <<= 1) {
        s0 += __shfl_xor(s0, d, 64);
        s1 += __shfl_xor(s1, d, 64);
    }
    if (lane == 0) {
        atomicAdd(&out[bg * BPB + wave], s0);      // 8 adds per element
        atomicAdd(&out[bg * BPB + wave + 8], s1);  // (one per chunk)
    }
}

// ---------- fallback (ws too small): naive but correct ----------
__global__ __launch_bounds__(256) void k_naive(const float* __restrict__ x0,
                                               const float* __restrict__ conj,
                                               const float* __restrict__ rw,
                                               float* __restrict__ out) {
    int b = blockIdx.x;
    int t = threadIdx.x;
    __shared__ float red[256];
    float acc = 0.0f;
    for (int c = t; c < C_; c += 256) {
        float m = 0.0f;
        for (int v = 0; v < V_; ++v) {
            float mu1 = 1.0f / (1.0f + expf(-conj[(size_t)c * TWOV + v]));
            float mu2 = 1.0f / (1.0f + expf(-conj[(size_t)c * TWOV + V_ + v]));
            float x = x0[(size_t)b * V_ + v];
            m = fmaxf(m, fmaxf(mu1 * (1.0f - x), mu2 * x));
        }
        acc += rw[c] * (1.0f - m);
    }
    red[t] = acc;
    __syncthreads();
    for (int s = 128; s > 0; s >>= 1) {
        if (t < s) red[t] += red[t + s];
        __syncthreads();
    }
    if (t == 0) out[b] = 5.0f + red[0];
}

extern "C" void kernel_launch(void* const* d_in, const int* in_sizes, int n_in,
                              void* d_out, int out_size, void* d_ws, size_t ws_size,
                              hipStream_t stream) {
    const float* x0   = (const float*)d_in[0];
    const float* conj = (const float*)d_in[1];
    const float* rw   = (const float*)d_in[2];
    float* out = (float*)d_out;

    const size_t mu_floats = (size_t)(V_ / 2) * C_ * 4;   // 262144 floats (1 MB)
    const size_t need = mu_floats * sizeof(float);

    if (ws_size < need) {
        k_naive<<<B_, 256, 0, stream>>>(x0, conj, rw, out);
        return;
    }

    float4* muT4 = (float4*)d_ws;

    k_prep<<<C_, 256, 0, stream>>>(conj, (float2*)muT4, out);
    dim3 grid(NBG, NCHUNK);   // 64 x 8 = 512 blocks; x-major = batch so
                              // concurrent blocks share the same mu chunk in L2
    k_main<<<grid, 512, 0, stream>>>(x0, muT4, rw, out);
}